// Round 12
// baseline (250.042 us; speedup 1.0000x reference)
//
#include <hip/hip_runtime.h>
#include <stdint.h>

typedef __attribute__((ext_vector_type(8))) short short8;   // 8 bf16 (4 VGPRs)
typedef __attribute__((ext_vector_type(4))) short short4b;  // 4 bf16 (2 VGPRs)
typedef __attribute__((ext_vector_type(4))) float f32x4;    // MFMA acc
typedef __attribute__((ext_vector_type(4))) unsigned short ushort4_t;

#define MFMA16(a, b, c) __builtin_amdgcn_mfma_f32_16x16x32_bf16((a), (b), (c), 0, 0, 0)

// 16x16x16 bf16 MFMA: device pass has the _1k builtin on gfx950; host gets a
// parse-only stub (host never executes device code).
#if defined(__HIP_DEVICE_COMPILE__)
  #if __has_builtin(__builtin_amdgcn_mfma_f32_16x16x16bf16_1k)
    #define MFMA16K16(a, b, c) __builtin_amdgcn_mfma_f32_16x16x16bf16_1k((a), (b), (c), 0, 0, 0)
  #else
    #define MFMA16K16(a, b, c) __builtin_amdgcn_mfma_f32_16x16x16_bf16((a), (b), (c), 0, 0, 0)
  #endif
#else
  #define MFMA16K16(a, b, c) (c)
#endif

#define SCL_F (0.125f * 1.44269504f)   // dk^-0.5 folded with log2(e)

__device__ __forceinline__ float b2f(unsigned short u) {
    union { unsigned u; float f; } c; c.u = ((unsigned)u) << 16; return c.f;
}
__device__ __forceinline__ unsigned short f2b(float f) {
    union { float f; unsigned u; } c; c.f = f;
    unsigned r = c.u + 0x7FFF + ((c.u >> 16) & 1);   // round-to-nearest-even
    return (unsigned short)(r >> 16);
}
__device__ __forceinline__ unsigned f_as_u(float f) {
    union { float f; unsigned u; } c; c.f = f; return c.u;
}

// async global->LDS, 16B per lane; LDS dest = wave-uniform base + lane*16.
__device__ __forceinline__ void g2lds16(const unsigned short* g, unsigned lds_byte_off) {
    __builtin_amdgcn_global_load_lds(
        (const __attribute__((address_space(1))) void*)(uintptr_t)g,
        (__attribute__((address_space(3))) void*)(uintptr_t)lds_byte_off,
        16, 0, 0);
}

// ---------------------------------------------------------------------------
// Dtype canary (proven): flag=1 => f32 inputs, 0 => bf16.
// ---------------------------------------------------------------------------
__global__ void detect_dtype(const unsigned short* __restrict__ x, int* __restrict__ flag) {
    __shared__ int cnt;
    if (threadIdx.x == 0) cnt = 0;
    __syncthreads();
    int insane = 0;
    #pragma unroll
    for (int j = 0; j < 4; ++j) {
        unsigned short u = x[threadIdx.x * 4 + j];
        int e = (u >> 7) & 0xFF;
        if ((e >= 1 && e <= 90) || e >= 165) insane++;
    }
    atomicAdd(&cnt, insane);
    __syncthreads();
    if (threadIdx.x == 0) *flag = (cnt > 128) ? 1 : 0;
}

// ---------------------------------------------------------------------------
// Fused convert+transpose for 4 weights (z=0..3), biases (z=4), and the
// x f32->bf16 conversion (z=5..12; early-exit when inputs already bf16).
// ---------------------------------------------------------------------------
__global__ __launch_bounds__(256) void convtrans_k(const void* __restrict__ s0, const void* __restrict__ s1,
                                                   const void* __restrict__ s2, const void* __restrict__ s3,
                                                   const void* __restrict__ b0, const void* __restrict__ b1,
                                                   const void* __restrict__ b2, const void* __restrict__ b3s,
                                                   const void* __restrict__ xsrc,
                                                   unsigned short* __restrict__ xdst,
                                                   unsigned short* __restrict__ dstBase,
                                                   unsigned short* __restrict__ dstB3,
                                                   unsigned short* __restrict__ dstBo,
                                                   const int* __restrict__ flag) {
    const int z = blockIdx.z;
    if (z >= 5) {           // x conversion: 8 slices x 256 blocks x 256 thr x 8 elems
        if (!*flag) return;
        const int slice = z - 5;
        const size_t i0 = (size_t)slice * 524288 + (blockIdx.y * 16 + blockIdx.x) * 2048 + threadIdx.x * 8;
        const float* s = (const float*)xsrc;
        float4 f0 = *(const float4*)&s[i0];
        float4 f1 = *(const float4*)&s[i0 + 4];
        unsigned short* t = &xdst[i0];
        t[0] = f2b(f0.x); t[1] = f2b(f0.y); t[2] = f2b(f0.z); t[3] = f2b(f0.w);
        t[4] = f2b(f1.x); t[5] = f2b(f1.y); t[6] = f2b(f1.z); t[7] = f2b(f1.w);
        return;
    }
    if (z == 4) {           // biases
        if (blockIdx.y != 0 || blockIdx.x >= 4) return;
        const int w = blockIdx.x;
        const void* src = (w == 0) ? b0 : (w == 1) ? b1 : (w == 2) ? b2 : b3s;
        #pragma unroll
        for (int j = 0; j < 4; ++j) {
            const int i = threadIdx.x * 4 + j;
            unsigned short v = (*flag) ? f2b(((const float*)src)[i]) : ((const unsigned short*)src)[i];
            if (w < 3) dstB3[w * 1024 + i] = v;
            else dstBo[i] = v;
        }
        return;
    }
    __shared__ __align__(16) unsigned short tile[64 * 72];
    const void* src = (z == 0) ? s0 : (z == 1) ? s1 : (z == 2) ? s2 : s3;
    unsigned short* dst = dstBase + (size_t)z * 1024 * 1024;
    const int tid = threadIdx.x;
    const int r0 = blockIdx.y * 64, c0 = blockIdx.x * 64;
    const int rb = tid >> 3, c = (tid & 7) * 8;
    if (*flag) {
        const float* s = (const float*)src;
        #pragma unroll
        for (int it = 0; it < 2; ++it) {
            int rr = it * 32 + rb;
            float4 f0 = *(const float4*)&s[(size_t)(r0 + rr) * 1024 + c0 + c];
            float4 f1 = *(const float4*)&s[(size_t)(r0 + rr) * 1024 + c0 + c + 4];
            unsigned short* t = &tile[rr * 72 + c];
            t[0] = f2b(f0.x); t[1] = f2b(f0.y); t[2] = f2b(f0.z); t[3] = f2b(f0.w);
            t[4] = f2b(f1.x); t[5] = f2b(f1.y); t[6] = f2b(f1.z); t[7] = f2b(f1.w);
        }
    } else {
        const unsigned short* s = (const unsigned short*)src;
        #pragma unroll
        for (int it = 0; it < 2; ++it) {
            int rr = it * 32 + rb;
            *(short8*)&tile[rr * 72 + c] = *(const short8*)&s[(size_t)(r0 + rr) * 1024 + c0 + c];
        }
    }
    __syncthreads();
    #pragma unroll
    for (int it = 0; it < 2; ++it) {
        int n = it * 32 + rb, k8 = c;
        union { short8 s; unsigned short u[8]; } tmp;
        #pragma unroll
        for (int j = 0; j < 8; ++j) tmp.u[j] = tile[(k8 + j) * 72 + n];
        *(short8*)&dst[(size_t)(c0 + n) * 1024 + r0 + k8] = tmp.s;
    }
}

// ---------------------------------------------------------------------------
// C = relu(A[M,K] @ BT[N,K]^T + bias[N]); m97 staging. BM=BN=128.
// mode 0: bf16. mode 1: final (f32/bf16 per flag).
// mode 2 (QKV): Q blocks (n0<1024) scaled by SCL post-relu; K blocks
//   (1024..2047) get masked seq rows ZEROED (=> S=0 => p=exp2(0)=1, exactly
//   the reference's exp(1e-9) path); V blocks stored transposed into VtG.
// ---------------------------------------------------------------------------
__global__ __launch_bounds__(256) void gemm_bias_relu(const unsigned short* __restrict__ A,
                                                      const void* __restrict__ Araw,
                                                      const unsigned short* __restrict__ BT,
                                                      const unsigned short* __restrict__ bias,
                                                      void* __restrict__ C,
                                                      unsigned short* __restrict__ VtG,
                                                      const int* __restrict__ mask,
                                                      const int* __restrict__ flag,
                                                      int M, int N, int K, int mode) {
    __shared__ __align__(16) unsigned short As[128 * 32];
    __shared__ __align__(16) unsigned short Bs[128 * 32];
    const int tid = threadIdx.x;
    const int wave = tid >> 6, lane = tid & 63;
    const int quad = lane >> 4, l16 = lane & 15;
    const int wm = wave >> 1, wn = wave & 1;
    const int m0 = blockIdx.y * 128, n0 = blockIdx.x * 128;

    const unsigned short* Ause = (Araw != nullptr && *flag == 0) ? (const unsigned short*)Araw : A;

    f32x4 acc[4][4];
    #pragma unroll
    for (int i = 0; i < 4; i++)
        #pragma unroll
        for (int j = 0; j < 4; j++) acc[i][j] = (f32x4){0.f, 0.f, 0.f, 0.f};

    const int srow = wave * 32 + (lane >> 2);
    const int sc8  = (lane & 3) * 8;
    const unsigned short* gA0 = Ause + (size_t)(m0 + srow) * K + sc8;
    const unsigned short* gA1 = gA0 + (size_t)16 * K;
    const unsigned short* gB0 = BT + (size_t)(n0 + srow) * K + sc8;
    const unsigned short* gB1 = gB0 + (size_t)16 * K;
    const unsigned ldsA = (unsigned)(uintptr_t)&As[0] + wave * 2048;
    const unsigned ldsB = (unsigned)(uintptr_t)&Bs[0] + wave * 2048;

    for (int k0 = 0; k0 < K; k0 += 32) {
        __syncthreads();
        g2lds16(gA0 + k0, ldsA);
        g2lds16(gA1 + k0, ldsA + 1024);
        g2lds16(gB0 + k0, ldsB);
        g2lds16(gB1 + k0, ldsB + 1024);
        __syncthreads();
        short8 af[4], bf[4];
        #pragma unroll
        for (int i = 0; i < 4; i++) af[i] = *(const short8*)&As[(wm * 64 + i * 16 + l16) * 32 + quad * 8];
        #pragma unroll
        for (int j = 0; j < 4; j++) bf[j] = *(const short8*)&Bs[(wn * 64 + j * 16 + l16) * 32 + quad * 8];
        #pragma unroll
        for (int i = 0; i < 4; i++)
            #pragma unroll
            for (int j = 0; j < 4; j++)
                acc[i][j] = MFMA16(af[i], bf[j], acc[i][j]);
    }

    if (mode == 2 && n0 >= 2048) {
        // V columns: write transposed into VtG[bh][dk][seq]
        #pragma unroll
        for (int j = 0; j < 4; j++) {
            const int col = n0 + wn * 64 + j * 16 + l16;
            const int h  = (col - 2048) >> 6;
            const int dk = (col - 2048) & 63;
            const float bj = b2f(bias[col]);
            #pragma unroll
            for (int i = 0; i < 4; i++) {
                const int rowb = m0 + wm * 64 + i * 16 + quad * 4;
                const int bb = rowb >> 11;
                const int s0 = rowb & 2047;
                ushort4_t w;
                #pragma unroll
                for (int r = 0; r < 4; r++) {
                    float v = acc[i][j][r] + bj;
                    v = v > 0.f ? v : 0.f;
                    w[r] = f2b(v);
                }
                *(ushort4_t*)&VtG[(size_t)((bb * 16 + h) * 64 + dk) * 2048 + s0] = w;
            }
        }
    } else if (mode == 2) {
        const int isQ = (n0 < 1024);
        #pragma unroll
        for (int j = 0; j < 4; j++) {
            const int col = n0 + wn * 64 + j * 16 + l16;
            const float bj = b2f(bias[col]);
            #pragma unroll
            for (int i = 0; i < 4; i++) {
                const int rowb = m0 + wm * 64 + i * 16 + quad * 4;
                #pragma unroll
                for (int r = 0; r < 4; r++) {
                    float v = acc[i][j][r] + bj;
                    v = v > 0.f ? v : 0.f;
                    if (isQ) {
                        v *= SCL_F;                       // fold dk^-0.5*log2e into Q
                    } else {
                        const int row = rowb + r;         // K: zero masked seq rows
                        if (mask[(row >> 11) * 2048 + (row & 2047)]) v = 0.f;
                    }
                    ((unsigned short*)C)[(size_t)(rowb + r) * N + col] = f2b(v);
                }
            }
        }
    } else {
        const int f32out = (mode == 1) && (*flag != 0);
        #pragma unroll
        for (int j = 0; j < 4; j++) {
            const int col = n0 + wn * 64 + j * 16 + l16;
            const float bj = b2f(bias[col]);
            #pragma unroll
            for (int i = 0; i < 4; i++) {
                const int rowb = m0 + wm * 64 + i * 16 + quad * 4;
                #pragma unroll
                for (int r = 0; r < 4; r++) {
                    float v = acc[i][j][r] + bj;
                    v = v > 0.f ? v : 0.f;
                    if (f32out) ((float*)C)[(size_t)(rowb + r) * N + col] = v;
                    else ((unsigned short*)C)[(size_t)(rowb + r) * N + col] = f2b(v);
                }
            }
        }
    }
}

// ---------------------------------------------------------------------------
// BM=64, BN=128 GEMM variant (final projection): grid 2x blocks of the 128
// version -> 2 blocks/CU instead of 1. Waves 2x2, each 32x64 (acc[2][4]).
// ---------------------------------------------------------------------------
__global__ __launch_bounds__(256) void gemm_bias_relu_64(const unsigned short* __restrict__ A,
                                                         const unsigned short* __restrict__ BT,
                                                         const unsigned short* __restrict__ bias,
                                                         void* __restrict__ C,
                                                         const int* __restrict__ flag,
                                                         int M, int N, int K) {
    __shared__ __align__(16) unsigned short As[64 * 32];
    __shared__ __align__(16) unsigned short Bs[128 * 32];
    const int tid = threadIdx.x;
    const int wave = tid >> 6, lane = tid & 63;
    const int quad = lane >> 4, l16 = lane & 15;
    const int wm = wave >> 1, wn = wave & 1;
    const int m0 = blockIdx.y * 64, n0 = blockIdx.x * 128;

    f32x4 acc[2][4];
    #pragma unroll
    for (int i = 0; i < 2; i++)
        #pragma unroll
        for (int j = 0; j < 4; j++) acc[i][j] = (f32x4){0.f, 0.f, 0.f, 0.f};

    const int sr16 = lane >> 2;         // 0..15
    const int sc8  = (lane & 3) * 8;
    const unsigned short* gA0 = A  + (size_t)(m0 + wave * 16 + sr16) * K + sc8;
    const unsigned short* gB0 = BT + (size_t)(n0 + wave * 32 + sr16) * K + sc8;
    const unsigned short* gB1 = gB0 + (size_t)16 * K;
    const unsigned ldsA = (unsigned)(uintptr_t)&As[0] + wave * 1024;
    const unsigned ldsB = (unsigned)(uintptr_t)&Bs[0] + wave * 2048;

    for (int k0 = 0; k0 < K; k0 += 32) {
        __syncthreads();
        g2lds16(gA0 + k0, ldsA);
        g2lds16(gB0 + k0, ldsB);
        g2lds16(gB1 + k0, ldsB + 1024);
        __syncthreads();
        short8 af[2], bf[4];
        #pragma unroll
        for (int i = 0; i < 2; i++) af[i] = *(const short8*)&As[(wm * 32 + i * 16 + l16) * 32 + quad * 8];
        #pragma unroll
        for (int j = 0; j < 4; j++) bf[j] = *(const short8*)&Bs[(wn * 64 + j * 16 + l16) * 32 + quad * 8];
        #pragma unroll
        for (int i = 0; i < 2; i++)
            #pragma unroll
            for (int j = 0; j < 4; j++)
                acc[i][j] = MFMA16(af[i], bf[j], acc[i][j]);
    }

    const int f32out = (*flag != 0);
    #pragma unroll
    for (int j = 0; j < 4; j++) {
        const int col = n0 + wn * 64 + j * 16 + l16;
        const float bj = b2f(bias[col]);
        #pragma unroll
        for (int i = 0; i < 2; i++) {
            const int rowb = m0 + wm * 32 + i * 16 + quad * 4;
            #pragma unroll
            for (int r = 0; r < 4; r++) {
                float v = acc[i][j][r] + bj;
                v = v > 0.f ? v : 0.f;
                if (f32out) ((float*)C)[(size_t)(rowb + r) * N + col] = v;
                else ((unsigned short*)C)[(size_t)(rowb + r) * N + col] = f2b(v);
            }
        }
    }
}

// ---------------------------------------------------------------------------
// Attention v4: S^T trick + ones-MFMA denominator + perm pack; mask and
// scale are now baked into Q/K by the QKV GEMM epilogue, so the inner loop
// is exp2(s) only — no mul, no mask, no maskF LDS.
// ---------------------------------------------------------------------------
__global__ __launch_bounds__(256) void attn_kernel(const unsigned short* __restrict__ qkv,
                                                   const unsigned short* __restrict__ VtG,
                                                   unsigned short* __restrict__ out) {
    __shared__ __align__(16) unsigned short Ks[64 * 72];    // [key][dk]
    __shared__ __align__(16) unsigned short Vs[64 * 72];    // [dk][key]

    const int qt = blockIdx.x, bh = blockIdx.y;
    const int b = bh >> 4, h = bh & 15;
    const int tid = threadIdx.x, wave = tid >> 6, lane = tid & 63;
    const int quad = lane >> 4, l16 = lane & 15;

    const int qrowA = qt * 128 + wave * 16 + l16;
    const unsigned short* qpA = qkv + (size_t)(b * 2048 + qrowA) * 3072 + h * 64;
    const unsigned short* qpB = qpA + (size_t)64 * 3072;
    const short8 qa0 = *(const short8*)(qpA + quad * 8);
    const short8 qa1 = *(const short8*)(qpA + 32 + quad * 8);
    const short8 qb0 = *(const short8*)(qpB + quad * 8);
    const short8 qb1 = *(const short8*)(qpB + 32 + quad * 8);

    f32x4 oA[4], oB[4], sumA, sumB;
    #pragma unroll
    for (int n = 0; n < 4; n++) { oA[n] = (f32x4){0.f,0.f,0.f,0.f}; oB[n] = (f32x4){0.f,0.f,0.f,0.f}; }
    sumA = (f32x4){0.f,0.f,0.f,0.f};
    sumB = (f32x4){0.f,0.f,0.f,0.f};

    const short4b ones = { (short)0x3F80, (short)0x3F80, (short)0x3F80, (short)0x3F80 };  // bf16 1.0

    const int srow = tid >> 2;          // 0..63
    const int scol = (tid & 3) * 16;    // 0,16,32,48
    const unsigned short* kg = qkv + (size_t)(b * 2048 + srow) * 3072 + 1024 + h * 64 + scol;
    const unsigned short* vg = VtG + (size_t)(bh * 64 + srow) * 2048 + scol;
    const size_t kstep = (size_t)64 * 3072;
    unsigned short* wK = &Ks[srow * 72 + scol];
    unsigned short* wV = &Vs[srow * 72 + scol];

    for (int kt = 0; kt < 32; ++kt) {
        __syncthreads();
        *(short8*)wK       = *(const short8*)(kg + kt * kstep);
        *(short8*)(wK + 8) = *(const short8*)(kg + kt * kstep + 8);
        *(short8*)wV       = *(const short8*)(vg + kt * 64);
        *(short8*)(wV + 8) = *(const short8*)(vg + kt * 64 + 8);
        __syncthreads();

        // S^T per 16-key subtile: acc[r] = S[q=l16][key=t*16+quad*4+r],
        // already scaled (Q pre-scaled); masked keys give S=0 (K row zeroed).
        f32x4 sA[4], sB[4];
        #pragma unroll
        for (int t = 0; t < 4; ++t) {
            const short8 kb0 = *(const short8*)&Ks[(t * 16 + l16) * 72 + quad * 8];
            const short8 kb1 = *(const short8*)&Ks[(t * 16 + l16) * 72 + 32 + quad * 8];
            f32x4 z = (f32x4){0.f, 0.f, 0.f, 0.f};
            sA[t] = MFMA16(kb1, qa1, MFMA16(kb0, qa0, z));
            sB[t] = MFMA16(kb1, qb1, MFMA16(kb0, qb0, z));
        }

        // V B-frags (16x16x16): B[k=t*16+quad*4+j][n=dkblk*16+l16]
        short4b vb[4][4];
        #pragma unroll
        for (int t = 0; t < 4; ++t)
            #pragma unroll
            for (int n = 0; n < 4; ++n)
                vb[t][n] = *(const short4b*)&Vs[(n * 16 + l16) * 72 + t * 16 + quad * 4];

        #pragma unroll
        for (int t = 0; t < 4; ++t) {
            float pA[4], pB[4];
            #pragma unroll
            for (int r = 0; r < 4; ++r) {
                pA[r] = exp2f(sA[t][r]);
                pB[r] = exp2f(sB[t][r]);
            }
            // truncating pack via v_perm (bytes {3,2} of each src pair)
            union { unsigned u[2]; short4b s; } fa, fb;
            fa.u[0] = __builtin_amdgcn_perm(f_as_u(pA[1]), f_as_u(pA[0]), 0x07060302u);
            fa.u[1] = __builtin_amdgcn_perm(f_as_u(pA[3]), f_as_u(pA[2]), 0x07060302u);
            fb.u[0] = __builtin_amdgcn_perm(f_as_u(pB[1]), f_as_u(pB[0]), 0x07060302u);
            fb.u[1] = __builtin_amdgcn_perm(f_as_u(pB[3]), f_as_u(pB[2]), 0x07060302u);
            #pragma unroll
            for (int n = 0; n < 4; ++n) {
                oA[n] = MFMA16K16(fa.s, vb[t][n], oA[n]);
                oB[n] = MFMA16K16(fb.s, vb[t][n], oB[n]);
            }
            sumA = MFMA16K16(fa.s, ones, sumA);   // row-sum of P -> C-layout rows
            sumB = MFMA16K16(fb.s, ones, sumB);
        }
    }

    float invA[4], invB[4];
    #pragma unroll
    for (int r = 0; r < 4; ++r) { invA[r] = 1.0f / sumA[r]; invB[r] = 1.0f / sumB[r]; }
    #pragma unroll
    for (int n = 0; n < 4; n++)
        #pragma unroll
        for (int r = 0; r < 4; r++) {
            const int row = qt * 128 + wave * 16 + quad * 4 + r;
            out[(size_t)(b * 2048 + row) * 1024 + h * 64 + n * 16 + l16] = f2b(oA[n][r] * invA[r]);
            out[(size_t)(b * 2048 + row + 64) * 1024 + h * 64 + n * 16 + l16] = f2b(oB[n][r] * invB[r]);
        }
}

// ---------------------------------------------------------------------------
extern "C" void kernel_launch(void* const* d_in, const int* in_sizes, int n_in,
                              void* d_out, int out_size, void* d_ws, size_t ws_size,
                              hipStream_t stream) {
    const void* x  = d_in[0];
    const int*  mk = (const int*)d_in[1];
    const void* Wq = d_in[2]; const void* bq = d_in[3];
    const void* Wk = d_in[4]; const void* bk = d_in[5];
    const void* Wv = d_in[6]; const void* bv = d_in[7];
    const void* Wo = d_in[8]; const void* bo = d_in[9];

    char* wsb = (char*)d_ws;
    int* flag = (int*)wsb;                                   // 64B header
    unsigned short* W0 = (unsigned short*)(wsb + 64);

    const size_t M1 = 1024u * 1024u;
    const size_t M4 = 4096u * 1024u;
    unsigned short* xb  = W0;                                // 4M elems (reused as abf)
    unsigned short* WT  = xb + M4;                           // 3M: Wq^T|Wk^T|Wv^T
    unsigned short* WoT = WT + 3 * M1;                       // 1M (contiguous after WT)
    unsigned short* b3  = WoT + M1;                          // 3072 (pad 4096)
    unsigned short* bob = b3 + 4096;                         // 1024
    unsigned short* qkv = bob + 1024;                        // 12M (V third unused)
    unsigned short* VtG = qkv + (size_t)4096 * 3072;         // 4M  (total ~48MB)
    unsigned short* abf = xb;                                // alias: x dead after QKV GEMM

    detect_dtype<<<1, 256, 0, stream>>>((const unsigned short*)x, flag);

    convtrans_k<<<dim3(16, 16, 13), 256, 0, stream>>>(Wq, Wk, Wv, Wo, bq, bk, bv, bo,
                                                      x, xb, WT, b3, bob, flag);

    gemm_bias_relu<<<dim3(24, 32), 256, 0, stream>>>(xb, x, WT, b3, qkv, VtG, mk, flag,
                                                     4096, 3072, 1024, 2);
    attn_kernel<<<dim3(16, 32), 256, 0, stream>>>(qkv, VtG, abf);
    gemm_bias_relu_64<<<dim3(8, 64), 256, 0, stream>>>(abf, WoT, bob, d_out, flag,
                                                       4096, 1024, 1024);
}

// Round 13
// 248.423 us; speedup vs baseline: 1.0065x; 1.0065x over previous
//
#include <hip/hip_runtime.h>
#include <stdint.h>

typedef __attribute__((ext_vector_type(8))) short short8;   // 8 bf16 (4 VGPRs)
typedef __attribute__((ext_vector_type(4))) short short4b;  // 4 bf16 (2 VGPRs)
typedef __attribute__((ext_vector_type(4))) float f32x4;    // MFMA acc
typedef __attribute__((ext_vector_type(4))) unsigned short ushort4_t;
typedef __attribute__((ext_vector_type(4))) int int4_t;

#define MFMA16(a, b, c) __builtin_amdgcn_mfma_f32_16x16x32_bf16((a), (b), (c), 0, 0, 0)

// 16x16x16 bf16 MFMA: device pass has the _1k builtin on gfx950; host gets a
// parse-only stub (host never executes device code).
#if defined(__HIP_DEVICE_COMPILE__)
  #if __has_builtin(__builtin_amdgcn_mfma_f32_16x16x16bf16_1k)
    #define MFMA16K16(a, b, c) __builtin_amdgcn_mfma_f32_16x16x16bf16_1k((a), (b), (c), 0, 0, 0)
  #else
    #define MFMA16K16(a, b, c) __builtin_amdgcn_mfma_f32_16x16x16_bf16((a), (b), (c), 0, 0, 0)
  #endif
#else
  #define MFMA16K16(a, b, c) (c)
#endif

#define SCL_F (0.125f * 1.44269504f)   // dk^-0.5 folded with log2(e)

__device__ __forceinline__ float b2f(unsigned short u) {
    union { unsigned u; float f; } c; c.u = ((unsigned)u) << 16; return c.f;
}
__device__ __forceinline__ unsigned short f2b(float f) {
    union { float f; unsigned u; } c; c.f = f;
    unsigned r = c.u + 0x7FFF + ((c.u >> 16) & 1);   // round-to-nearest-even
    return (unsigned short)(r >> 16);
}
__device__ __forceinline__ unsigned f_as_u(float f) {
    union { float f; unsigned u; } c; c.f = f; return c.u;
}

// async global->LDS, 16B per lane; LDS dest = wave-uniform base + lane*16.
__device__ __forceinline__ void g2lds16(const unsigned short* g, unsigned lds_byte_off) {
    __builtin_amdgcn_global_load_lds(
        (const __attribute__((address_space(1))) void*)(uintptr_t)g,
        (__attribute__((address_space(3))) void*)(uintptr_t)lds_byte_off,
        16, 0, 0);
}

// ---------------------------------------------------------------------------
// Dtype canary (proven): flag=1 => f32 inputs, 0 => bf16.
// ---------------------------------------------------------------------------
__global__ void detect_dtype(const unsigned short* __restrict__ x, int* __restrict__ flag) {
    __shared__ int cnt;
    if (threadIdx.x == 0) cnt = 0;
    __syncthreads();
    int insane = 0;
    #pragma unroll
    for (int j = 0; j < 4; ++j) {
        unsigned short u = x[threadIdx.x * 4 + j];
        int e = (u >> 7) & 0xFF;
        if ((e >= 1 && e <= 90) || e >= 165) insane++;
    }
    atomicAdd(&cnt, insane);
    __syncthreads();
    if (threadIdx.x == 0) *flag = (cnt > 128) ? 1 : 0;
}

// ---------------------------------------------------------------------------
// Fused convert+transpose for 4 weights (z=0..3), biases (z=4), and the
// x f32->bf16 conversion (z=5..12; early-exit when inputs already bf16).
// ---------------------------------------------------------------------------
__global__ __launch_bounds__(256) void convtrans_k(const void* __restrict__ s0, const void* __restrict__ s1,
                                                   const void* __restrict__ s2, const void* __restrict__ s3,
                                                   const void* __restrict__ b0, const void* __restrict__ b1,
                                                   const void* __restrict__ b2, const void* __restrict__ b3s,
                                                   const void* __restrict__ xsrc,
                                                   unsigned short* __restrict__ xdst,
                                                   unsigned short* __restrict__ dstBase,
                                                   unsigned short* __restrict__ dstB3,
                                                   unsigned short* __restrict__ dstBo,
                                                   const int* __restrict__ flag) {
    const int z = blockIdx.z;
    if (z >= 5) {           // x conversion: 8 slices x 256 blocks x 256 thr x 8 elems
        if (!*flag) return;
        const int slice = z - 5;
        const size_t i0 = (size_t)slice * 524288 + (blockIdx.y * 16 + blockIdx.x) * 2048 + threadIdx.x * 8;
        const float* s = (const float*)xsrc;
        float4 f0 = *(const float4*)&s[i0];
        float4 f1 = *(const float4*)&s[i0 + 4];
        unsigned short* t = &xdst[i0];
        t[0] = f2b(f0.x); t[1] = f2b(f0.y); t[2] = f2b(f0.z); t[3] = f2b(f0.w);
        t[4] = f2b(f1.x); t[5] = f2b(f1.y); t[6] = f2b(f1.z); t[7] = f2b(f1.w);
        return;
    }
    if (z == 4) {           // biases
        if (blockIdx.y != 0 || blockIdx.x >= 4) return;
        const int w = blockIdx.x;
        const void* src = (w == 0) ? b0 : (w == 1) ? b1 : (w == 2) ? b2 : b3s;
        #pragma unroll
        for (int j = 0; j < 4; ++j) {
            const int i = threadIdx.x * 4 + j;
            unsigned short v = (*flag) ? f2b(((const float*)src)[i]) : ((const unsigned short*)src)[i];
            if (w < 3) dstB3[w * 1024 + i] = v;
            else dstBo[i] = v;
        }
        return;
    }
    __shared__ __align__(16) unsigned short tile[64 * 72];
    const void* src = (z == 0) ? s0 : (z == 1) ? s1 : (z == 2) ? s2 : s3;
    unsigned short* dst = dstBase + (size_t)z * 1024 * 1024;
    const int tid = threadIdx.x;
    const int r0 = blockIdx.y * 64, c0 = blockIdx.x * 64;
    const int rb = tid >> 3, c = (tid & 7) * 8;
    if (*flag) {
        const float* s = (const float*)src;
        #pragma unroll
        for (int it = 0; it < 2; ++it) {
            int rr = it * 32 + rb;
            float4 f0 = *(const float4*)&s[(size_t)(r0 + rr) * 1024 + c0 + c];
            float4 f1 = *(const float4*)&s[(size_t)(r0 + rr) * 1024 + c0 + c + 4];
            unsigned short* t = &tile[rr * 72 + c];
            t[0] = f2b(f0.x); t[1] = f2b(f0.y); t[2] = f2b(f0.z); t[3] = f2b(f0.w);
            t[4] = f2b(f1.x); t[5] = f2b(f1.y); t[6] = f2b(f1.z); t[7] = f2b(f1.w);
        }
    } else {
        const unsigned short* s = (const unsigned short*)src;
        #pragma unroll
        for (int it = 0; it < 2; ++it) {
            int rr = it * 32 + rb;
            *(short8*)&tile[rr * 72 + c] = *(const short8*)&s[(size_t)(r0 + rr) * 1024 + c0 + c];
        }
    }
    __syncthreads();
    #pragma unroll
    for (int it = 0; it < 2; ++it) {
        int n = it * 32 + rb, k8 = c;
        union { short8 s; unsigned short u[8]; } tmp;
        #pragma unroll
        for (int j = 0; j < 8; ++j) tmp.u[j] = tile[(k8 + j) * 72 + n];
        *(short8*)&dst[(size_t)(c0 + n) * 1024 + r0 + k8] = tmp.s;
    }
}

// ---------------------------------------------------------------------------
// C = relu(A[M,K] @ BT[N,K]^T + bias[N]); m97 staging. BM=BN=128.
// mode 0: bf16. mode 1: final (f32/bf16 per flag).
// mode 2 (QKV): Q blocks scaled by SCL; K blocks get masked seq rows zeroed
//   (mask loads hoisted: one int4 per i-block, outside the j loop);
//   V blocks stored transposed into VtG.
// ---------------------------------------------------------------------------
__global__ __launch_bounds__(256) void gemm_bias_relu(const unsigned short* __restrict__ A,
                                                      const void* __restrict__ Araw,
                                                      const unsigned short* __restrict__ BT,
                                                      const unsigned short* __restrict__ bias,
                                                      void* __restrict__ C,
                                                      unsigned short* __restrict__ VtG,
                                                      const int* __restrict__ mask,
                                                      const int* __restrict__ flag,
                                                      int M, int N, int K, int mode) {
    __shared__ __align__(16) unsigned short As[128 * 32];
    __shared__ __align__(16) unsigned short Bs[128 * 32];
    const int tid = threadIdx.x;
    const int wave = tid >> 6, lane = tid & 63;
    const int quad = lane >> 4, l16 = lane & 15;
    const int wm = wave >> 1, wn = wave & 1;
    const int m0 = blockIdx.y * 128, n0 = blockIdx.x * 128;

    const unsigned short* Ause = (Araw != nullptr && *flag == 0) ? (const unsigned short*)Araw : A;

    f32x4 acc[4][4];
    #pragma unroll
    for (int i = 0; i < 4; i++)
        #pragma unroll
        for (int j = 0; j < 4; j++) acc[i][j] = (f32x4){0.f, 0.f, 0.f, 0.f};

    const int srow = wave * 32 + (lane >> 2);
    const int sc8  = (lane & 3) * 8;
    const unsigned short* gA0 = Ause + (size_t)(m0 + srow) * K + sc8;
    const unsigned short* gA1 = gA0 + (size_t)16 * K;
    const unsigned short* gB0 = BT + (size_t)(n0 + srow) * K + sc8;
    const unsigned short* gB1 = gB0 + (size_t)16 * K;
    const unsigned ldsA = (unsigned)(uintptr_t)&As[0] + wave * 2048;
    const unsigned ldsB = (unsigned)(uintptr_t)&Bs[0] + wave * 2048;

    for (int k0 = 0; k0 < K; k0 += 32) {
        __syncthreads();
        g2lds16(gA0 + k0, ldsA);
        g2lds16(gA1 + k0, ldsA + 1024);
        g2lds16(gB0 + k0, ldsB);
        g2lds16(gB1 + k0, ldsB + 1024);
        __syncthreads();
        short8 af[4], bf[4];
        #pragma unroll
        for (int i = 0; i < 4; i++) af[i] = *(const short8*)&As[(wm * 64 + i * 16 + l16) * 32 + quad * 8];
        #pragma unroll
        for (int j = 0; j < 4; j++) bf[j] = *(const short8*)&Bs[(wn * 64 + j * 16 + l16) * 32 + quad * 8];
        #pragma unroll
        for (int i = 0; i < 4; i++)
            #pragma unroll
            for (int j = 0; j < 4; j++)
                acc[i][j] = MFMA16(af[i], bf[j], acc[i][j]);
    }

    if (mode == 2 && n0 >= 2048) {
        // V columns: write transposed into VtG[bh][dk][seq]
        #pragma unroll
        for (int j = 0; j < 4; j++) {
            const int col = n0 + wn * 64 + j * 16 + l16;
            const int h  = (col - 2048) >> 6;
            const int dk = (col - 2048) & 63;
            const float bj = b2f(bias[col]);
            #pragma unroll
            for (int i = 0; i < 4; i++) {
                const int rowb = m0 + wm * 64 + i * 16 + quad * 4;
                const int bb = rowb >> 11;
                const int s0 = rowb & 2047;
                ushort4_t w;
                #pragma unroll
                for (int r = 0; r < 4; r++) {
                    float v = acc[i][j][r] + bj;
                    v = v > 0.f ? v : 0.f;
                    w[r] = f2b(v);
                }
                *(ushort4_t*)&VtG[(size_t)((bb * 16 + h) * 64 + dk) * 2048 + s0] = w;
            }
        }
    } else if (mode == 2) {
        const int isQ = (n0 < 1024);
        // hoisted mask: mask[(row>>11)*2048+(row&2047)] == mask[row]; rows
        // rowb..rowb+3 are consecutive & 4-aligned -> one int4 per i-block.
        int4_t mv[4];
        if (!isQ) {
            #pragma unroll
            for (int i = 0; i < 4; i++)
                mv[i] = *(const int4_t*)&mask[m0 + wm * 64 + i * 16 + quad * 4];
        }
        #pragma unroll
        for (int j = 0; j < 4; j++) {
            const int col = n0 + wn * 64 + j * 16 + l16;
            const float bj = b2f(bias[col]);
            #pragma unroll
            for (int i = 0; i < 4; i++) {
                const int rowb = m0 + wm * 64 + i * 16 + quad * 4;
                #pragma unroll
                for (int r = 0; r < 4; r++) {
                    float v = acc[i][j][r] + bj;
                    v = v > 0.f ? v : 0.f;
                    if (isQ) v *= SCL_F;                  // fold dk^-0.5*log2e into Q
                    else if (mv[i][r]) v = 0.f;           // K: zero masked seq rows
                    ((unsigned short*)C)[(size_t)(rowb + r) * N + col] = f2b(v);
                }
            }
        }
    } else {
        const int f32out = (mode == 1) && (*flag != 0);
        #pragma unroll
        for (int j = 0; j < 4; j++) {
            const int col = n0 + wn * 64 + j * 16 + l16;
            const float bj = b2f(bias[col]);
            #pragma unroll
            for (int i = 0; i < 4; i++) {
                const int rowb = m0 + wm * 64 + i * 16 + quad * 4;
                #pragma unroll
                for (int r = 0; r < 4; r++) {
                    float v = acc[i][j][r] + bj;
                    v = v > 0.f ? v : 0.f;
                    if (f32out) ((float*)C)[(size_t)(rowb + r) * N + col] = v;
                    else ((unsigned short*)C)[(size_t)(rowb + r) * N + col] = f2b(v);
                }
            }
        }
    }
}

// ---------------------------------------------------------------------------
// Attention v4 (round-12 proven): S^T trick + ones-MFMA denominator + perm
// pack; mask/scale baked into Q/K upstream — inner loop is exp2(s) only.
// ---------------------------------------------------------------------------
__global__ __launch_bounds__(256) void attn_kernel(const unsigned short* __restrict__ qkv,
                                                   const unsigned short* __restrict__ VtG,
                                                   unsigned short* __restrict__ out) {
    __shared__ __align__(16) unsigned short Ks[64 * 72];    // [key][dk]
    __shared__ __align__(16) unsigned short Vs[64 * 72];    // [dk][key]

    const int qt = blockIdx.x, bh = blockIdx.y;
    const int b = bh >> 4, h = bh & 15;
    const int tid = threadIdx.x, wave = tid >> 6, lane = tid & 63;
    const int quad = lane >> 4, l16 = lane & 15;

    const int qrowA = qt * 128 + wave * 16 + l16;
    const unsigned short* qpA = qkv + (size_t)(b * 2048 + qrowA) * 3072 + h * 64;
    const unsigned short* qpB = qpA + (size_t)64 * 3072;
    const short8 qa0 = *(const short8*)(qpA + quad * 8);
    const short8 qa1 = *(const short8*)(qpA + 32 + quad * 8);
    const short8 qb0 = *(const short8*)(qpB + quad * 8);
    const short8 qb1 = *(const short8*)(qpB + 32 + quad * 8);

    f32x4 oA[4], oB[4], sumA, sumB;
    #pragma unroll
    for (int n = 0; n < 4; n++) { oA[n] = (f32x4){0.f,0.f,0.f,0.f}; oB[n] = (f32x4){0.f,0.f,0.f,0.f}; }
    sumA = (f32x4){0.f,0.f,0.f,0.f};
    sumB = (f32x4){0.f,0.f,0.f,0.f};

    const short4b ones = { (short)0x3F80, (short)0x3F80, (short)0x3F80, (short)0x3F80 };  // bf16 1.0

    const int srow = tid >> 2;          // 0..63
    const int scol = (tid & 3) * 16;    // 0,16,32,48
    const unsigned short* kg = qkv + (size_t)(b * 2048 + srow) * 3072 + 1024 + h * 64 + scol;
    const unsigned short* vg = VtG + (size_t)(bh * 64 + srow) * 2048 + scol;
    const size_t kstep = (size_t)64 * 3072;
    unsigned short* wK = &Ks[srow * 72 + scol];
    unsigned short* wV = &Vs[srow * 72 + scol];

    for (int kt = 0; kt < 32; ++kt) {
        __syncthreads();
        *(short8*)wK       = *(const short8*)(kg + kt * kstep);
        *(short8*)(wK + 8) = *(const short8*)(kg + kt * kstep + 8);
        *(short8*)wV       = *(const short8*)(vg + kt * 64);
        *(short8*)(wV + 8) = *(const short8*)(vg + kt * 64 + 8);
        __syncthreads();

        // S^T per 16-key subtile: acc[r] = S[q=l16][key=t*16+quad*4+r],
        // already scaled (Q pre-scaled); masked keys give S=0 (K row zeroed).
        f32x4 sA[4], sB[4];
        #pragma unroll
        for (int t = 0; t < 4; ++t) {
            const short8 kb0 = *(const short8*)&Ks[(t * 16 + l16) * 72 + quad * 8];
            const short8 kb1 = *(const short8*)&Ks[(t * 16 + l16) * 72 + 32 + quad * 8];
            f32x4 z = (f32x4){0.f, 0.f, 0.f, 0.f};
            sA[t] = MFMA16(kb1, qa1, MFMA16(kb0, qa0, z));
            sB[t] = MFMA16(kb1, qb1, MFMA16(kb0, qb0, z));
        }

        // V B-frags (16x16x16): B[k=t*16+quad*4+j][n=dkblk*16+l16]
        short4b vb[4][4];
        #pragma unroll
        for (int t = 0; t < 4; ++t)
            #pragma unroll
            for (int n = 0; n < 4; ++n)
                vb[t][n] = *(const short4b*)&Vs[(n * 16 + l16) * 72 + t * 16 + quad * 4];

        #pragma unroll
        for (int t = 0; t < 4; ++t) {
            float pA[4], pB[4];
            #pragma unroll
            for (int r = 0; r < 4; ++r) {
                pA[r] = exp2f(sA[t][r]);
                pB[r] = exp2f(sB[t][r]);
            }
            // truncating pack via v_perm (bytes {3,2} of each src pair)
            union { unsigned u[2]; short4b s; } fa, fb;
            fa.u[0] = __builtin_amdgcn_perm(f_as_u(pA[1]), f_as_u(pA[0]), 0x07060302u);
            fa.u[1] = __builtin_amdgcn_perm(f_as_u(pA[3]), f_as_u(pA[2]), 0x07060302u);
            fb.u[0] = __builtin_amdgcn_perm(f_as_u(pB[1]), f_as_u(pB[0]), 0x07060302u);
            fb.u[1] = __builtin_amdgcn_perm(f_as_u(pB[3]), f_as_u(pB[2]), 0x07060302u);
            #pragma unroll
            for (int n = 0; n < 4; ++n) {
                oA[n] = MFMA16K16(fa.s, vb[t][n], oA[n]);
                oB[n] = MFMA16K16(fb.s, vb[t][n], oB[n]);
            }
            sumA = MFMA16K16(fa.s, ones, sumA);   // row-sum of P -> C-layout rows
            sumB = MFMA16K16(fb.s, ones, sumB);
        }
    }

    float invA[4], invB[4];
    #pragma unroll
    for (int r = 0; r < 4; ++r) { invA[r] = 1.0f / sumA[r]; invB[r] = 1.0f / sumB[r]; }
    #pragma unroll
    for (int n = 0; n < 4; n++)
        #pragma unroll
        for (int r = 0; r < 4; r++) {
            const int row = qt * 128 + wave * 16 + quad * 4 + r;
            out[(size_t)(b * 2048 + row) * 1024 + h * 64 + n * 16 + l16] = f2b(oA[n][r] * invA[r]);
            out[(size_t)(b * 2048 + row + 64) * 1024 + h * 64 + n * 16 + l16] = f2b(oB[n][r] * invB[r]);
        }
}

// ---------------------------------------------------------------------------
extern "C" void kernel_launch(void* const* d_in, const int* in_sizes, int n_in,
                              void* d_out, int out_size, void* d_ws, size_t ws_size,
                              hipStream_t stream) {
    const void* x  = d_in[0];
    const int*  mk = (const int*)d_in[1];
    const void* Wq = d_in[2]; const void* bq = d_in[3];
    const void* Wk = d_in[4]; const void* bk = d_in[5];
    const void* Wv = d_in[6]; const void* bv = d_in[7];
    const void* Wo = d_in[8]; const void* bo = d_in[9];

    char* wsb = (char*)d_ws;
    int* flag = (int*)wsb;                                   // 64B header
    unsigned short* W0 = (unsigned short*)(wsb + 64);

    const size_t M1 = 1024u * 1024u;
    const size_t M4 = 4096u * 1024u;
    unsigned short* xb  = W0;                                // 4M elems (reused as abf)
    unsigned short* WT  = xb + M4;                           // 3M: Wq^T|Wk^T|Wv^T
    unsigned short* WoT = WT + 3 * M1;                       // 1M (contiguous after WT)
    unsigned short* b3  = WoT + M1;                          // 3072 (pad 4096)
    unsigned short* bob = b3 + 4096;                         // 1024
    unsigned short* qkv = bob + 1024;                        // 12M (V third unused)
    unsigned short* VtG = qkv + (size_t)4096 * 3072;         // 4M  (total ~48MB)
    unsigned short* abf = xb;                                // alias: x dead after QKV GEMM

    detect_dtype<<<1, 256, 0, stream>>>((const unsigned short*)x, flag);

    convtrans_k<<<dim3(16, 16, 13), 256, 0, stream>>>(Wq, Wk, Wv, Wo, bq, bk, bv, bo,
                                                      x, xb, WT, b3, bob, flag);

    gemm_bias_relu<<<dim3(24, 32), 256, 0, stream>>>(xb, x, WT, b3, qkv, VtG, mk, flag,
                                                     4096, 3072, 1024, 2);
    attn_kernel<<<dim3(16, 32), 256, 0, stream>>>(qkv, VtG, abf);
    gemm_bias_relu<<<dim3(8, 32), 256, 0, stream>>>(abf, nullptr, WoT, bob, d_out, VtG, mk, flag,
                                                    4096, 1024, 1024, 1);
}

// Round 14
// 232.817 us; speedup vs baseline: 1.0740x; 1.0670x over previous
//
#include <hip/hip_runtime.h>
#include <stdint.h>

typedef __attribute__((ext_vector_type(8))) short short8;   // 8 bf16 (4 VGPRs)
typedef __attribute__((ext_vector_type(4))) short short4b;  // 4 bf16 (2 VGPRs)
typedef __attribute__((ext_vector_type(4))) float f32x4;    // MFMA acc
typedef __attribute__((ext_vector_type(4))) unsigned short ushort4_t;

#define MFMA16(a, b, c) __builtin_amdgcn_mfma_f32_16x16x32_bf16((a), (b), (c), 0, 0, 0)

// 16x16x16 bf16 MFMA: device pass has the _1k builtin on gfx950; host gets a
// parse-only stub (host never executes device code).
#if defined(__HIP_DEVICE_COMPILE__)
  #if __has_builtin(__builtin_amdgcn_mfma_f32_16x16x16bf16_1k)
    #define MFMA16K16(a, b, c) __builtin_amdgcn_mfma_f32_16x16x16bf16_1k((a), (b), (c), 0, 0, 0)
  #else
    #define MFMA16K16(a, b, c) __builtin_amdgcn_mfma_f32_16x16x16_bf16((a), (b), (c), 0, 0, 0)
  #endif
#else
  #define MFMA16K16(a, b, c) (c)
#endif

#define SCL_F (0.125f * 1.44269504f)   // dk^-0.5 folded with log2(e)

__device__ __forceinline__ float b2f(unsigned short u) {
    union { unsigned u; float f; } c; c.u = ((unsigned)u) << 16; return c.f;
}
__device__ __forceinline__ unsigned short f2b(float f) {
    union { float f; unsigned u; } c; c.f = f;
    unsigned r = c.u + 0x7FFF + ((c.u >> 16) & 1);   // round-to-nearest-even
    return (unsigned short)(r >> 16);
}
__device__ __forceinline__ unsigned f_as_u(float f) {
    union { float f; unsigned u; } c; c.f = f; return c.u;
}

// async global->LDS, 16B per lane; LDS dest = wave-uniform base + lane*16.
__device__ __forceinline__ void g2lds16(const unsigned short* g, unsigned lds_byte_off) {
    __builtin_amdgcn_global_load_lds(
        (const __attribute__((address_space(1))) void*)(uintptr_t)g,
        (__attribute__((address_space(3))) void*)(uintptr_t)lds_byte_off,
        16, 0, 0);
}

// ---------------------------------------------------------------------------
// Dtype canary (proven): flag=1 => f32 inputs, 0 => bf16.
// ---------------------------------------------------------------------------
__global__ void detect_dtype(const unsigned short* __restrict__ x, int* __restrict__ flag) {
    __shared__ int cnt;
    if (threadIdx.x == 0) cnt = 0;
    __syncthreads();
    int insane = 0;
    #pragma unroll
    for (int j = 0; j < 4; ++j) {
        unsigned short u = x[threadIdx.x * 4 + j];
        int e = (u >> 7) & 0xFF;
        if ((e >= 1 && e <= 90) || e >= 165) insane++;
    }
    atomicAdd(&cnt, insane);
    __syncthreads();
    if (threadIdx.x == 0) *flag = (cnt > 128) ? 1 : 0;
}

// ---------------------------------------------------------------------------
// Fused convert+transpose for 4 weights (z=0..3), biases (z=4), and the
// x f32->bf16 conversion (z=5..12). Wq (z=0) and bq (w=0) are SCALED by
// SCL_F: relu(x@Wq+bq)*s == relu(x@(Wq*s)+bq*s) for s>0 — folds the
// softmax scale into Q at zero runtime cost.
// ---------------------------------------------------------------------------
__global__ __launch_bounds__(256) void convtrans_k(const void* __restrict__ s0, const void* __restrict__ s1,
                                                   const void* __restrict__ s2, const void* __restrict__ s3,
                                                   const void* __restrict__ b0, const void* __restrict__ b1,
                                                   const void* __restrict__ b2, const void* __restrict__ b3s,
                                                   const void* __restrict__ xsrc,
                                                   unsigned short* __restrict__ xdst,
                                                   unsigned short* __restrict__ dstBase,
                                                   unsigned short* __restrict__ dstB3,
                                                   unsigned short* __restrict__ dstBo,
                                                   const int* __restrict__ flag) {
    const int z = blockIdx.z;
    if (z >= 5) {           // x conversion: 8 slices x 256 blocks x 256 thr x 8 elems
        if (!*flag) return;
        const int slice = z - 5;
        const size_t i0 = (size_t)slice * 524288 + (blockIdx.y * 16 + blockIdx.x) * 2048 + threadIdx.x * 8;
        const float* s = (const float*)xsrc;
        float4 f0 = *(const float4*)&s[i0];
        float4 f1 = *(const float4*)&s[i0 + 4];
        unsigned short* t = &xdst[i0];
        t[0] = f2b(f0.x); t[1] = f2b(f0.y); t[2] = f2b(f0.z); t[3] = f2b(f0.w);
        t[4] = f2b(f1.x); t[5] = f2b(f1.y); t[6] = f2b(f1.z); t[7] = f2b(f1.w);
        return;
    }
    if (z == 4) {           // biases (bq scaled by SCL_F)
        if (blockIdx.y != 0 || blockIdx.x >= 4) return;
        const int w = blockIdx.x;
        const void* src = (w == 0) ? b0 : (w == 1) ? b1 : (w == 2) ? b2 : b3s;
        const float bscl = (w == 0) ? SCL_F : 1.0f;
        #pragma unroll
        for (int j = 0; j < 4; ++j) {
            const int i = threadIdx.x * 4 + j;
            float fv = (*flag) ? ((const float*)src)[i] : b2f(((const unsigned short*)src)[i]);
            unsigned short v = f2b(fv * bscl);
            if (w < 3) dstB3[w * 1024 + i] = v;
            else dstBo[i] = v;
        }
        return;
    }
    __shared__ __align__(16) unsigned short tile[64 * 72];
    const void* src = (z == 0) ? s0 : (z == 1) ? s1 : (z == 2) ? s2 : s3;
    unsigned short* dst = dstBase + (size_t)z * 1024 * 1024;
    const float wscl = (z == 0) ? SCL_F : 1.0f;
    const int tid = threadIdx.x;
    const int r0 = blockIdx.y * 64, c0 = blockIdx.x * 64;
    const int rb = tid >> 3, c = (tid & 7) * 8;
    if (*flag) {
        const float* s = (const float*)src;
        #pragma unroll
        for (int it = 0; it < 2; ++it) {
            int rr = it * 32 + rb;
            float4 f0 = *(const float4*)&s[(size_t)(r0 + rr) * 1024 + c0 + c];
            float4 f1 = *(const float4*)&s[(size_t)(r0 + rr) * 1024 + c0 + c + 4];
            unsigned short* t = &tile[rr * 72 + c];
            t[0] = f2b(f0.x * wscl); t[1] = f2b(f0.y * wscl); t[2] = f2b(f0.z * wscl); t[3] = f2b(f0.w * wscl);
            t[4] = f2b(f1.x * wscl); t[5] = f2b(f1.y * wscl); t[6] = f2b(f1.z * wscl); t[7] = f2b(f1.w * wscl);
        }
    } else if (z == 0) {
        const unsigned short* s = (const unsigned short*)src;
        #pragma unroll
        for (int it = 0; it < 2; ++it) {
            int rr = it * 32 + rb;
            union { short8 v; unsigned short u[8]; } in;
            in.v = *(const short8*)&s[(size_t)(r0 + rr) * 1024 + c0 + c];
            unsigned short* t = &tile[rr * 72 + c];
            #pragma unroll
            for (int j = 0; j < 8; ++j) t[j] = f2b(b2f(in.u[j]) * SCL_F);
        }
    } else {
        const unsigned short* s = (const unsigned short*)src;
        #pragma unroll
        for (int it = 0; it < 2; ++it) {
            int rr = it * 32 + rb;
            *(short8*)&tile[rr * 72 + c] = *(const short8*)&s[(size_t)(r0 + rr) * 1024 + c0 + c];
        }
    }
    __syncthreads();
    #pragma unroll
    for (int it = 0; it < 2; ++it) {
        int n = it * 32 + rb, k8 = c;
        union { short8 s; unsigned short u[8]; } tmp;
        #pragma unroll
        for (int j = 0; j < 8; ++j) tmp.u[j] = tile[(k8 + j) * 72 + n];
        *(short8*)&dst[(size_t)(c0 + n) * 1024 + r0 + k8] = tmp.s;
    }
}

// ---------------------------------------------------------------------------
// Zero masked seq rows in the K third of qkv (=> S=0 => p=exp2(0)=1, exactly
// the reference's exp(1e-9) path). ~4 MB of stores, ~1-2 us.
// One block per 2 rows; thread t covers 8 cols of row b*2 + (t>>7).
// ---------------------------------------------------------------------------
__global__ __launch_bounds__(256) void mask_k(unsigned short* __restrict__ qkv,
                                              const int* __restrict__ mask) {
    const int row = blockIdx.x * 2 + (threadIdx.x >> 7);      // 0..4095 == [b][seq]
    const int col = (threadIdx.x & 127) * 8;
    if (mask[row]) {
        const short8 z = {0, 0, 0, 0, 0, 0, 0, 0};
        *(short8*)&qkv[(size_t)row * 3072 + 1024 + col] = z;
    }
}

// ---------------------------------------------------------------------------
// C = relu(A[M,K] @ BT[N,K]^T + bias[N]); m97 staging. BM=BN=128.
// mode 0: bf16. mode 1: final (f32/bf16 per flag).
// mode 2 (QKV): V blocks (n0>=2048) stored transposed into VtG; Q/K plain
// (scale/mask handled upstream/downstream — round-11 epilogue, minimal regs).
// ---------------------------------------------------------------------------
__global__ __launch_bounds__(256) void gemm_bias_relu(const unsigned short* __restrict__ A,
                                                      const void* __restrict__ Araw,
                                                      const unsigned short* __restrict__ BT,
                                                      const unsigned short* __restrict__ bias,
                                                      void* __restrict__ C,
                                                      unsigned short* __restrict__ VtG,
                                                      const int* __restrict__ flag,
                                                      int M, int N, int K, int mode) {
    __shared__ __align__(16) unsigned short As[128 * 32];
    __shared__ __align__(16) unsigned short Bs[128 * 32];
    const int tid = threadIdx.x;
    const int wave = tid >> 6, lane = tid & 63;
    const int quad = lane >> 4, l16 = lane & 15;
    const int wm = wave >> 1, wn = wave & 1;
    const int m0 = blockIdx.y * 128, n0 = blockIdx.x * 128;

    const unsigned short* Ause = (Araw != nullptr && *flag == 0) ? (const unsigned short*)Araw : A;

    f32x4 acc[4][4];
    #pragma unroll
    for (int i = 0; i < 4; i++)
        #pragma unroll
        for (int j = 0; j < 4; j++) acc[i][j] = (f32x4){0.f, 0.f, 0.f, 0.f};

    const int srow = wave * 32 + (lane >> 2);
    const int sc8  = (lane & 3) * 8;
    const unsigned short* gA0 = Ause + (size_t)(m0 + srow) * K + sc8;
    const unsigned short* gA1 = gA0 + (size_t)16 * K;
    const unsigned short* gB0 = BT + (size_t)(n0 + srow) * K + sc8;
    const unsigned short* gB1 = gB0 + (size_t)16 * K;
    const unsigned ldsA = (unsigned)(uintptr_t)&As[0] + wave * 2048;
    const unsigned ldsB = (unsigned)(uintptr_t)&Bs[0] + wave * 2048;

    for (int k0 = 0; k0 < K; k0 += 32) {
        __syncthreads();
        g2lds16(gA0 + k0, ldsA);
        g2lds16(gA1 + k0, ldsA + 1024);
        g2lds16(gB0 + k0, ldsB);
        g2lds16(gB1 + k0, ldsB + 1024);
        __syncthreads();
        short8 af[4], bf[4];
        #pragma unroll
        for (int i = 0; i < 4; i++) af[i] = *(const short8*)&As[(wm * 64 + i * 16 + l16) * 32 + quad * 8];
        #pragma unroll
        for (int j = 0; j < 4; j++) bf[j] = *(const short8*)&Bs[(wn * 64 + j * 16 + l16) * 32 + quad * 8];
        #pragma unroll
        for (int i = 0; i < 4; i++)
            #pragma unroll
            for (int j = 0; j < 4; j++)
                acc[i][j] = MFMA16(af[i], bf[j], acc[i][j]);
    }

    if (mode == 2 && n0 >= 2048) {
        // V columns: write transposed into VtG[bh][dk][seq]
        #pragma unroll
        for (int j = 0; j < 4; j++) {
            const int col = n0 + wn * 64 + j * 16 + l16;
            const int h  = (col - 2048) >> 6;
            const int dk = (col - 2048) & 63;
            const float bj = b2f(bias[col]);
            #pragma unroll
            for (int i = 0; i < 4; i++) {
                const int rowb = m0 + wm * 64 + i * 16 + quad * 4;
                const int bb = rowb >> 11;
                const int s0 = rowb & 2047;
                ushort4_t w;
                #pragma unroll
                for (int r = 0; r < 4; r++) {
                    float v = acc[i][j][r] + bj;
                    v = v > 0.f ? v : 0.f;
                    w[r] = f2b(v);
                }
                *(ushort4_t*)&VtG[(size_t)((bb * 16 + h) * 64 + dk) * 2048 + s0] = w;
            }
        }
    } else {
        const int f32out = (mode == 1) && (*flag != 0);
        #pragma unroll
        for (int j = 0; j < 4; j++) {
            const int col = n0 + wn * 64 + j * 16 + l16;
            const float bj = b2f(bias[col]);
            #pragma unroll
            for (int i = 0; i < 4; i++) {
                const int rowb = m0 + wm * 64 + i * 16 + quad * 4;
                #pragma unroll
                for (int r = 0; r < 4; r++) {
                    float v = acc[i][j][r] + bj;
                    v = v > 0.f ? v : 0.f;
                    if (f32out) ((float*)C)[(size_t)(rowb + r) * N + col] = v;
                    else ((unsigned short*)C)[(size_t)(rowb + r) * N + col] = f2b(v);
                }
            }
        }
    }
}

// ---------------------------------------------------------------------------
// Attention v4 (round-12 proven): S^T trick + ones-MFMA denominator + perm
// pack; mask/scale baked into Q/K upstream — inner loop is exp2(s) only.
// ---------------------------------------------------------------------------
__global__ __launch_bounds__(256) void attn_kernel(const unsigned short* __restrict__ qkv,
                                                   const unsigned short* __restrict__ VtG,
                                                   unsigned short* __restrict__ out) {
    __shared__ __align__(16) unsigned short Ks[64 * 72];    // [key][dk]
    __shared__ __align__(16) unsigned short Vs[64 * 72];    // [dk][key]

    const int qt = blockIdx.x, bh = blockIdx.y;
    const int b = bh >> 4, h = bh & 15;
    const int tid = threadIdx.x, wave = tid >> 6, lane = tid & 63;
    const int quad = lane >> 4, l16 = lane & 15;

    const int qrowA = qt * 128 + wave * 16 + l16;
    const unsigned short* qpA = qkv + (size_t)(b * 2048 + qrowA) * 3072 + h * 64;
    const unsigned short* qpB = qpA + (size_t)64 * 3072;
    const short8 qa0 = *(const short8*)(qpA + quad * 8);
    const short8 qa1 = *(const short8*)(qpA + 32 + quad * 8);
    const short8 qb0 = *(const short8*)(qpB + quad * 8);
    const short8 qb1 = *(const short8*)(qpB + 32 + quad * 8);

    f32x4 oA[4], oB[4], sumA, sumB;
    #pragma unroll
    for (int n = 0; n < 4; n++) { oA[n] = (f32x4){0.f,0.f,0.f,0.f}; oB[n] = (f32x4){0.f,0.f,0.f,0.f}; }
    sumA = (f32x4){0.f,0.f,0.f,0.f};
    sumB = (f32x4){0.f,0.f,0.f,0.f};

    const short4b ones = { (short)0x3F80, (short)0x3F80, (short)0x3F80, (short)0x3F80 };  // bf16 1.0

    const int srow = tid >> 2;          // 0..63
    const int scol = (tid & 3) * 16;    // 0,16,32,48
    const unsigned short* kg = qkv + (size_t)(b * 2048 + srow) * 3072 + 1024 + h * 64 + scol;
    const unsigned short* vg = VtG + (size_t)(bh * 64 + srow) * 2048 + scol;
    const size_t kstep = (size_t)64 * 3072;
    unsigned short* wK = &Ks[srow * 72 + scol];
    unsigned short* wV = &Vs[srow * 72 + scol];

    for (int kt = 0; kt < 32; ++kt) {
        __syncthreads();
        *(short8*)wK       = *(const short8*)(kg + kt * kstep);
        *(short8*)(wK + 8) = *(const short8*)(kg + kt * kstep + 8);
        *(short8*)wV       = *(const short8*)(vg + kt * 64);
        *(short8*)(wV + 8) = *(const short8*)(vg + kt * 64 + 8);
        __syncthreads();

        // S^T per 16-key subtile: acc[r] = S[q=l16][key=t*16+quad*4+r],
        // already scaled (Wq pre-scaled); masked keys give S=0 (K row zeroed).
        f32x4 sA[4], sB[4];
        #pragma unroll
        for (int t = 0; t < 4; ++t) {
            const short8 kb0 = *(const short8*)&Ks[(t * 16 + l16) * 72 + quad * 8];
            const short8 kb1 = *(const short8*)&Ks[(t * 16 + l16) * 72 + 32 + quad * 8];
            f32x4 z = (f32x4){0.f, 0.f, 0.f, 0.f};
            sA[t] = MFMA16(kb1, qa1, MFMA16(kb0, qa0, z));
            sB[t] = MFMA16(kb1, qb1, MFMA16(kb0, qb0, z));
        }

        // V B-frags (16x16x16): B[k=t*16+quad*4+j][n=dkblk*16+l16]
        short4b vb[4][4];
        #pragma unroll
        for (int t = 0; t < 4; ++t)
            #pragma unroll
            for (int n = 0; n < 4; ++n)
                vb[t][n] = *(const short4b*)&Vs[(n * 16 + l16) * 72 + t * 16 + quad * 4];

        #pragma unroll
        for (int t = 0; t < 4; ++t) {
            float pA[4], pB[4];
            #pragma unroll
            for (int r = 0; r < 4; ++r) {
                pA[r] = exp2f(sA[t][r]);
                pB[r] = exp2f(sB[t][r]);
            }
            // truncating pack via v_perm (bytes {3,2} of each src pair)
            union { unsigned u[2]; short4b s; } fa, fb;
            fa.u[0] = __builtin_amdgcn_perm(f_as_u(pA[1]), f_as_u(pA[0]), 0x07060302u);
            fa.u[1] = __builtin_amdgcn_perm(f_as_u(pA[3]), f_as_u(pA[2]), 0x07060302u);
            fb.u[0] = __builtin_amdgcn_perm(f_as_u(pB[1]), f_as_u(pB[0]), 0x07060302u);
            fb.u[1] = __builtin_amdgcn_perm(f_as_u(pB[3]), f_as_u(pB[2]), 0x07060302u);
            #pragma unroll
            for (int n = 0; n < 4; ++n) {
                oA[n] = MFMA16K16(fa.s, vb[t][n], oA[n]);
                oB[n] = MFMA16K16(fb.s, vb[t][n], oB[n]);
            }
            sumA = MFMA16K16(fa.s, ones, sumA);   // row-sum of P -> C-layout rows
            sumB = MFMA16K16(fb.s, ones, sumB);
        }
    }

    float invA[4], invB[4];
    #pragma unroll
    for (int r = 0; r < 4; ++r) { invA[r] = 1.0f / sumA[r]; invB[r] = 1.0f / sumB[r]; }
    #pragma unroll
    for (int n = 0; n < 4; n++)
        #pragma unroll
        for (int r = 0; r < 4; r++) {
            const int row = qt * 128 + wave * 16 + quad * 4 + r;
            out[(size_t)(b * 2048 + row) * 1024 + h * 64 + n * 16 + l16] = f2b(oA[n][r] * invA[r]);
            out[(size_t)(b * 2048 + row + 64) * 1024 + h * 64 + n * 16 + l16] = f2b(oB[n][r] * invB[r]);
        }
}

// ---------------------------------------------------------------------------
extern "C" void kernel_launch(void* const* d_in, const int* in_sizes, int n_in,
                              void* d_out, int out_size, void* d_ws, size_t ws_size,
                              hipStream_t stream) {
    const void* x  = d_in[0];
    const int*  mk = (const int*)d_in[1];
    const void* Wq = d_in[2]; const void* bq = d_in[3];
    const void* Wk = d_in[4]; const void* bk = d_in[5];
    const void* Wv = d_in[6]; const void* bv = d_in[7];
    const void* Wo = d_in[8]; const void* bo = d_in[9];

    char* wsb = (char*)d_ws;
    int* flag = (int*)wsb;                                   // 64B header
    unsigned short* W0 = (unsigned short*)(wsb + 64);

    const size_t M1 = 1024u * 1024u;
    const size_t M4 = 4096u * 1024u;
    unsigned short* xb  = W0;                                // 4M elems (reused as abf)
    unsigned short* WT  = xb + M4;                           // 3M: Wq^T|Wk^T|Wv^T
    unsigned short* WoT = WT + 3 * M1;                       // 1M (contiguous after WT)
    unsigned short* b3  = WoT + M1;                          // 3072 (pad 4096)
    unsigned short* bob = b3 + 4096;                         // 1024
    unsigned short* qkv = bob + 1024;                        // 12M (V third unused)
    unsigned short* VtG = qkv + (size_t)4096 * 3072;         // 4M  (total ~48MB)
    unsigned short* abf = xb;                                // alias: x dead after QKV GEMM

    detect_dtype<<<1, 256, 0, stream>>>((const unsigned short*)x, flag);

    convtrans_k<<<dim3(16, 16, 13), 256, 0, stream>>>(Wq, Wk, Wv, Wo, bq, bk, bv, bo,
                                                      x, xb, WT, b3, bob, flag);

    gemm_bias_relu<<<dim3(24, 32), 256, 0, stream>>>(xb, x, WT, b3, qkv, VtG, flag,
                                                     4096, 3072, 1024, 2);
    mask_k<<<2048, 256, 0, stream>>>(qkv, mk);
    attn_kernel<<<dim3(16, 32), 256, 0, stream>>>(qkv, VtG, abf);
    gemm_bias_relu<<<dim3(8, 32), 256, 0, stream>>>(abf, nullptr, WoT, bob, d_out, VtG, flag,
                                                    4096, 1024, 1024, 1);
}